// Round 5
// baseline (3167.295 us; speedup 1.0000x reference)
//
#include <hip/hip_runtime.h>

#define W_  512
#define H_  512
#define HW  (512 * 512)      // 2^18
#define P_  20
#define B_  8
#define TL_ 29
#define IL_ 9

#define NB  1024             // co-resident: VGPR~20 -> 4 blocks/CU x 256 CU (proven R4)
#define NT  256
#define TOT (NB * NT)        // 262144 threads
#define PPT (B_ * HW / TOT)  // 8 pixels/thread, strided by TOT (lanes stride-1)

// Whole 20-step advect scan in one persistent kernel.
// Barrier v2: arrive via ONE fetch_add per block; last arriver release-stores a
// generation flag; others poll with agent-scope ACQUIRE LOADS (concurrent, no
// line ownership ping-pong — R4's RMW-poll convoy was the 2.5ms regression).
__global__ __launch_bounds__(NT, 4) void fused_scan(
    const float* __restrict__ frames,     // (B, TL, H, W, 1)
    const float* __restrict__ motion,     // (B, 2P, H, W)
    const float* __restrict__ intensity,  // (B, P, H, W)
    float*                    evo_result, // (B, P, H, W)  written + re-read (no restrict!)
    float* __restrict__       evo_motion, // (B, P, H, W)  write-only
    float* __restrict__       motion_out, // (B, 2P, H, W) write-only copy
    unsigned*                 barcnt,     // [0]=arrive counter, zeroed pre-launch
    unsigned*                 goflag)     // [0]=generation flag, zeroed pre-launch
{
    const int tid = blockIdx.x * NT + threadIdx.x;

    for (int p = 0; p < P_; ++p) {
        const float scale = (p == 0) ? 1.0f : 128.0f;

        for (int j = 0; j < PPT; ++j) {
            const int px  = j * TOT + tid;     // lanes stride-1 over pixels
            const int b   = px >> 18;          // / HW
            const int rem = px & (HW - 1);
            const int y   = rem >> 9;
            const int x   = rem & (W_ - 1);

            const float* prev = (p == 0)
                ? frames + ((long)b * TL_ + (IL_ - 1)) * HW
                : evo_result + ((long)b * P_ + (p - 1)) * HW;

            const long mo0 = ((long)b * (2 * P_) + 2 * p) * HW + rem; // flow-x
            const long io  = ((long)b * P_ + p) * HW + rem;           // inten/out

            float f0 = motion[mo0];
            float f1 = motion[mo0 + HW];
            float iv = intensity[io];
            motion_out[mo0]      = f0;   // pure-copy output, from registers
            motion_out[mo0 + HW] = f1;

            float cx = fminf(fmaxf((float)x + f0, 0.0f), 511.0f);
            float cy = fminf(fmaxf((float)y + f1, 0.0f), 511.0f);

            float x0f = floorf(cx), y0f = floorf(cy);
            float wx = cx - x0f, wy = cy - y0f;
            int x0 = (int)x0f, y0 = (int)y0f;
            int x1 = min(x0 + 1, W_ - 1), y1 = min(y0 + 1, H_ - 1);

            const float* r0 = prev + y0 * W_;
            const float* r1 = prev + y1 * W_;
            float v00 = r0[x0], v01 = r0[x1];
            float v10 = r1[x0], v11 = r1[x1];
            float bil = scale * ((1.0f - wy) * ((1.0f - wx) * v00 + wx * v01)
                                       + wy  * ((1.0f - wx) * v10 + wx * v11));

            int xi = (int)rintf(cx);   // half-to-even == jnp.round
            int yi = (int)rintf(cy);
            float res = (scale * prev[yi * W_ + xi] + iv) * 0.0078125f; // /128 exact

            evo_result[io] = res;
            evo_motion[io] = bil;
        }

        if (p != P_ - 1) {             // grid barrier between steps
            __syncthreads();
            if (threadIdx.x == 0) {
                __threadfence();       // release: make this block's writes visible
                unsigned old = __hip_atomic_fetch_add(barcnt, 1u,
                                    __ATOMIC_ACQ_REL, __HIP_MEMORY_SCOPE_AGENT);
                const unsigned target = (unsigned)(p + 1) * NB;
                const unsigned gen    = (unsigned)(p + 1);
                if (old + 1 == target) {
                    __hip_atomic_store(goflag, gen,
                                       __ATOMIC_RELEASE, __HIP_MEMORY_SCOPE_AGENT);
                } else {
                    while (__hip_atomic_load(goflag,
                               __ATOMIC_ACQUIRE, __HIP_MEMORY_SCOPE_AGENT) < gen)
                        __builtin_amdgcn_s_sleep(16);   // ~1k cycles backoff
                }
                __threadfence();       // acquire: invalidate stale cached data
            }
            __syncthreads();
        }
    }
}

extern "C" void kernel_launch(void* const* d_in, const int* in_sizes, int n_in,
                              void* d_out, int out_size, void* d_ws, size_t ws_size,
                              hipStream_t stream)
{
    const float* frames    = (const float*)d_in[0];
    const float* motion    = (const float*)d_in[1];
    const float* intensity = (const float*)d_in[2];

    float* out        = (float*)d_out;
    float* evo_result = out;                          // B*P*HW
    float* evo_motion = out + (long)B_ * P_ * HW;     // B*P*HW
    float* motion_out = out + 2L * B_ * P_ * HW;      // B*2P*HW
    unsigned* barcnt  = (unsigned*)d_ws;
    unsigned* goflag  = barcnt + 1;

    hipMemsetAsync(barcnt, 0, 2 * sizeof(unsigned), stream);  // reset each call

    fused_scan<<<dim3(NB), dim3(NT), 0, stream>>>(
        frames, motion, intensity, evo_result, evo_motion, motion_out,
        barcnt, goflag);
}

// Round 6
// 2028.396 us; speedup vs baseline: 1.5615x; 1.5615x over previous
//
#include <hip/hip_runtime.h>

#define W_  512
#define H_  512
#define HW  (512 * 512)      // 2^18
#define P_  20
#define B_  8
#define TL_ 29
#define IL_ 9

#define NB  1024             // co-resident: VGPR~20 -> 4 blocks/CU x 256 CU (proven R4/R5)
#define NT  256
#define TOT (NB * NT)        // 262144 threads
#define PPT (B_ * HW / TOT)  // 8 pixels/thread, strided by TOT (lanes stride-1)

// Carry traffic goes through the coherent point (MALL) with relaxed agent-scope
// atomics: sc0 sc1 ops, NO buffer_wbl2/buffer_inv. R4/R5 showed the per-leader
// L2 writeback/invalidate fences cost ~150us per barrier; this removes them.
__device__ __forceinline__ float carry_load(const float* p) {
    return __hip_atomic_load(p, __ATOMIC_RELAXED, __HIP_MEMORY_SCOPE_AGENT);
}
__device__ __forceinline__ void carry_store(float* p, float v) {
    __hip_atomic_store(p, v, __ATOMIC_RELAXED, __HIP_MEMORY_SCOPE_AGENT);
}

__global__ __launch_bounds__(NT, 4) void fused_scan(
    const float* __restrict__ frames,     // (B, TL, H, W, 1)
    const float* __restrict__ motion,     // (B, 2P, H, W)
    const float* __restrict__ intensity,  // (B, P, H, W)
    float*                    evo_result, // (B, P, H, W)  carry: MALL-coherent ops only
    float* __restrict__       evo_motion, // (B, P, H, W)  write-only, cached
    float* __restrict__       motion_out, // (B, 2P, H, W) write-only copy, cached
    unsigned*                 barcnt,     // arrive counter, zeroed pre-launch
    unsigned*                 goflag)     // generation flag, zeroed pre-launch
{
    const int tid = blockIdx.x * NT + threadIdx.x;

    for (int p = 0; p < P_; ++p) {
        const bool  first = (p == 0);
        const float scale = first ? 1.0f : 128.0f;

        for (int j = 0; j < PPT; ++j) {
            const int px  = j * TOT + tid;     // lanes stride-1 over pixels
            const int b   = px >> 18;          // / HW
            const int rem = px & (HW - 1);
            const int y   = rem >> 9;
            const int x   = rem & (W_ - 1);

            const float* prev = first
                ? frames + ((long)b * TL_ + (IL_ - 1)) * HW
                : evo_result + ((long)b * P_ + (p - 1)) * HW;

            const long mo0 = ((long)b * (2 * P_) + 2 * p) * HW + rem; // flow-x
            const long io  = ((long)b * P_ + p) * HW + rem;           // inten/out

            float f0 = motion[mo0];
            float f1 = motion[mo0 + HW];
            float iv = intensity[io];
            motion_out[mo0]      = f0;   // pure-copy output, from registers
            motion_out[mo0 + HW] = f1;

            float cx = fminf(fmaxf((float)x + f0, 0.0f), 511.0f);
            float cy = fminf(fmaxf((float)y + f1, 0.0f), 511.0f);

            float x0f = floorf(cx), y0f = floorf(cy);
            float wx = cx - x0f, wy = cy - y0f;
            int x0 = (int)x0f, y0 = (int)y0f;
            int x1 = min(x0 + 1, W_ - 1), y1 = min(y0 + 1, H_ - 1);
            int xi = (int)rintf(cx);   // half-to-even == jnp.round
            int yi = (int)rintf(cy);

            float v00, v01, v10, v11, vn;
            if (first) {               // wave-uniform branch
                v00 = prev[y0 * W_ + x0];  v01 = prev[y0 * W_ + x1];
                v10 = prev[y1 * W_ + x0];  v11 = prev[y1 * W_ + x1];
                vn  = prev[yi * W_ + xi];
            } else {                   // coherent-point gathers (see carry_load)
                v00 = carry_load(prev + y0 * W_ + x0);
                v01 = carry_load(prev + y0 * W_ + x1);
                v10 = carry_load(prev + y1 * W_ + x0);
                v11 = carry_load(prev + y1 * W_ + x1);
                vn  = carry_load(prev + yi * W_ + xi);
            }

            float bil = scale * ((1.0f - wy) * ((1.0f - wx) * v00 + wx * v01)
                                       + wy  * ((1.0f - wx) * v10 + wx * v11));
            float res = (scale * vn + iv) * 0.0078125f;   // /128 exact (pow2)

            carry_store(&evo_result[io], res);   // write-through to MALL
            evo_motion[io] = bil;
        }

        if (p != P_ - 1) {             // lightweight grid barrier (no L2 wb/inv)
            __syncthreads();
            if (threadIdx.x == 0) {
                // all this block's carry stores complete at the coherent point:
                asm volatile("s_waitcnt vmcnt(0)" ::: "memory");
                unsigned old = __hip_atomic_fetch_add(barcnt, 1u,
                                   __ATOMIC_RELAXED, __HIP_MEMORY_SCOPE_AGENT);
                const unsigned gen    = (unsigned)(p + 1);
                const unsigned target = gen * NB;
                if (old + 1 == target) {
                    __hip_atomic_store(goflag, gen,
                                       __ATOMIC_RELAXED, __HIP_MEMORY_SCOPE_AGENT);
                } else {
                    while (__hip_atomic_load(goflag,
                               __ATOMIC_RELAXED, __HIP_MEMORY_SCOPE_AGENT) < gen)
                        __builtin_amdgcn_s_sleep(2);
                }
                asm volatile("" ::: "memory");   // no hoisting past the spin
            }
            __syncthreads();
        }
    }
}

extern "C" void kernel_launch(void* const* d_in, const int* in_sizes, int n_in,
                              void* d_out, int out_size, void* d_ws, size_t ws_size,
                              hipStream_t stream)
{
    const float* frames    = (const float*)d_in[0];
    const float* motion    = (const float*)d_in[1];
    const float* intensity = (const float*)d_in[2];

    float* out        = (float*)d_out;
    float* evo_result = out;                          // B*P*HW
    float* evo_motion = out + (long)B_ * P_ * HW;     // B*P*HW
    float* motion_out = out + 2L * B_ * P_ * HW;      // B*2P*HW
    unsigned* barcnt  = (unsigned*)d_ws;
    unsigned* goflag  = barcnt + 1;

    hipMemsetAsync(barcnt, 0, 2 * sizeof(unsigned), stream);  // reset each call

    fused_scan<<<dim3(NB), dim3(NT), 0, stream>>>(
        frames, motion, intensity, evo_result, evo_motion, motion_out,
        barcnt, goflag);
}

// Round 7
// 336.511 us; speedup vs baseline: 9.4122x; 6.0277x over previous
//
#include <hip/hip_runtime.h>

#define W_  512
#define H_  512
#define HW  (512 * 512)   // 2^18
#define P_  20
#define B_  8
#define TL_ 29
#define IL_ 9

// One advect step, 1 px/thread, lanes stride-1 over pixels (R1's proven
// coalescing). Also emits this step's two motion_out planes from registers
// (kills the separate 672MB-traffic memcpy). Carry for p>0 reads
// evo_result[p-1]*128 — exact, pow2 scaling commutes with the lerp.
// NT hints: motion/intensity are read-once streams; evo_motion/motion_out are
// write-only. evo_result writes stay cached: the same blockIdx (=> same XCD)
// re-reads that range next launch, so gathers can hit per-XCD L2.
__global__ __launch_bounds__(256) void step_kernel(
    const float* __restrict__ prev_base,   // carry source, per-batch stride prev_stride
    long prev_stride,
    float prev_scale,                      // 1.0 frames / 128.0 evo_result readback
    const float* __restrict__ motion,      // (B, 2P, H, W)
    const float* __restrict__ intensity,   // (B, P, H, W)
    float* __restrict__ evo_result,        // (B, P, H, W)
    float* __restrict__ evo_motion,        // (B, P, H, W)
    float* __restrict__ motion_out,        // (B, 2P, H, W)
    int p)
{
    const int idx = blockIdx.x * blockDim.x + threadIdx.x;   // 1 px/thread
    const int b   = idx >> 18;           // / HW
    const int rem = idx & (HW - 1);
    const int y   = rem >> 9;
    const int x   = rem & (W_ - 1);

    const float* prev = prev_base + (long)b * prev_stride;

    const long mo0 = ((long)b * (2 * P_) + 2 * p) * HW + rem;  // flow-x plane
    const long io  = ((long)b * P_ + p) * HW + rem;            // intensity/outputs

    const float f0 = __builtin_nontemporal_load(motion + mo0);
    const float f1 = __builtin_nontemporal_load(motion + mo0 + HW);
    const float iv = __builtin_nontemporal_load(intensity + io);

    // motion_ output = pure copy, from registers
    __builtin_nontemporal_store(f0, motion_out + mo0);
    __builtin_nontemporal_store(f1, motion_out + mo0 + HW);

    const float cx = fminf(fmaxf((float)x + f0, 0.0f), 511.0f);
    const float cy = fminf(fmaxf((float)y + f1, 0.0f), 511.0f);

    const float x0f = floorf(cx), y0f = floorf(cy);
    const float wx = cx - x0f, wy = cy - y0f;
    const int x0 = (int)x0f, y0 = (int)y0f;
    const int x1 = min(x0 + 1, W_ - 1), y1 = min(y0 + 1, H_ - 1);

    const float* r0 = prev + y0 * W_;
    const float* r1 = prev + y1 * W_;
    const float v00 = r0[x0], v01 = r0[x1];
    const float v10 = r1[x0], v11 = r1[x1];
    const float bil = prev_scale * ((1.0f - wy) * ((1.0f - wx) * v00 + wx * v01)
                                          + wy  * ((1.0f - wx) * v10 + wx * v11));

    const int xi = (int)rintf(cx);   // half-to-even == jnp.round
    const int yi = (int)rintf(cy);
    const float res = (prev_scale * prev[yi * W_ + xi] + iv) * 0.0078125f; // /128

    evo_result[io] = res;                              // cached (re-read next step)
    __builtin_nontemporal_store(bil, evo_motion + io); // write-only
}

extern "C" void kernel_launch(void* const* d_in, const int* in_sizes, int n_in,
                              void* d_out, int out_size, void* d_ws, size_t ws_size,
                              hipStream_t stream)
{
    const float* frames    = (const float*)d_in[0];  // (B, TL, H, W, 1)
    const float* motion    = (const float*)d_in[1];  // (B, 2P, H, W)
    const float* intensity = (const float*)d_in[2];  // (B, P, H, W)

    float* out        = (float*)d_out;
    float* evo_result = out;                          // B*P*HW
    float* evo_motion = out + (long)B_ * P_ * HW;     // B*P*HW
    float* motion_out = out + 2L * B_ * P_ * HW;      // B*2P*HW

    const int threads = 256;
    const int blocks  = (B_ * HW) / threads;          // 8192

    // step 0: carry = frames[:, IL-1, :, :, 0]
    step_kernel<<<blocks, threads, 0, stream>>>(
        frames + (long)(IL_ - 1) * HW, (long)TL_ * HW, 1.0f,
        motion, intensity, evo_result, evo_motion, motion_out, 0);

    // steps 1..P-1: carry = evo_result[:, p-1] * 128 (exact)
    for (int p = 1; p < P_; ++p) {
        step_kernel<<<blocks, threads, 0, stream>>>(
            evo_result + (long)(p - 1) * HW, (long)P_ * HW, 128.0f,
            motion, intensity, evo_result, evo_motion, motion_out, p);
    }
}

// Round 8
// 328.351 us; speedup vs baseline: 9.6461x; 1.0248x over previous
//
#include <hip/hip_runtime.h>

#define W_  512
#define H_  512
#define HW  (512 * 512)   // 2^18
#define P_  20
#define B_  8
#define TL_ 29
#define IL_ 9

// One advect step, 1 px/thread, lanes stride-1 (proven R7 structure).
// R8 change: batch->XCD affinity. Blocks dispatch round-robin over the 8 XCDs
// (bid % 8), so batch b = bid & 7 puts every block of a batch on one XCD for
// ALL 20 launches. Each batch's 1 MB carry plane then lives in that XCD's 4 MB
// L2 across the write(step p) -> gather(step p+1) chain: L2-hit gathers, less
// HBM refetch. Streams still coalesced (block owns 256 consecutive px).
__global__ __launch_bounds__(256) void step_kernel(
    const float* __restrict__ prev_base,   // carry source, per-batch stride prev_stride
    long prev_stride,
    float prev_scale,                      // 1.0 frames / 128.0 evo_result readback
    const float* __restrict__ motion,      // (B, 2P, H, W)
    const float* __restrict__ intensity,   // (B, P, H, W)
    float* __restrict__ evo_result,        // (B, P, H, W)
    float* __restrict__ evo_motion,        // (B, P, H, W)
    float* __restrict__ motion_out,        // (B, 2P, H, W)
    int p)
{
    const int b   = blockIdx.x & 7;                       // batch -> XCD (round-robin)
    const int rem = ((blockIdx.x >> 3) << 8) + threadIdx.x; // pixel within image
    const int y   = rem >> 9;
    const int x   = rem & (W_ - 1);

    const float* prev = prev_base + (long)b * prev_stride;

    const long mo0 = ((long)b * (2 * P_) + 2 * p) * HW + rem;  // flow-x plane
    const long io  = ((long)b * P_ + p) * HW + rem;            // intensity/outputs

    const float f0 = __builtin_nontemporal_load(motion + mo0);
    const float f1 = __builtin_nontemporal_load(motion + mo0 + HW);
    const float iv = __builtin_nontemporal_load(intensity + io);

    // motion_ output = pure copy, from registers
    __builtin_nontemporal_store(f0, motion_out + mo0);
    __builtin_nontemporal_store(f1, motion_out + mo0 + HW);

    const float cx = fminf(fmaxf((float)x + f0, 0.0f), 511.0f);
    const float cy = fminf(fmaxf((float)y + f1, 0.0f), 511.0f);

    const float x0f = floorf(cx), y0f = floorf(cy);
    const float wx = cx - x0f, wy = cy - y0f;
    const int x0 = (int)x0f, y0 = (int)y0f;
    const int x1 = min(x0 + 1, W_ - 1), y1 = min(y0 + 1, H_ - 1);

    const float* r0 = prev + y0 * W_;
    const float* r1 = prev + y1 * W_;
    const float v00 = r0[x0], v01 = r0[x1];
    const float v10 = r1[x0], v11 = r1[x1];
    const float bil = prev_scale * ((1.0f - wy) * ((1.0f - wx) * v00 + wx * v01)
                                          + wy  * ((1.0f - wx) * v10 + wx * v11));

    const int xi = (int)rintf(cx);   // half-to-even == jnp.round
    const int yi = (int)rintf(cy);
    const float res = (prev_scale * prev[yi * W_ + xi] + iv) * 0.0078125f; // /128

    evo_result[io] = res;                              // cached: re-read next step, same XCD
    __builtin_nontemporal_store(bil, evo_motion + io); // write-only
}

extern "C" void kernel_launch(void* const* d_in, const int* in_sizes, int n_in,
                              void* d_out, int out_size, void* d_ws, size_t ws_size,
                              hipStream_t stream)
{
    const float* frames    = (const float*)d_in[0];  // (B, TL, H, W, 1)
    const float* motion    = (const float*)d_in[1];  // (B, 2P, H, W)
    const float* intensity = (const float*)d_in[2];  // (B, P, H, W)

    float* out        = (float*)d_out;
    float* evo_result = out;                          // B*P*HW
    float* evo_motion = out + (long)B_ * P_ * HW;     // B*P*HW
    float* motion_out = out + 2L * B_ * P_ * HW;      // B*2P*HW

    const int threads = 256;
    const int blocks  = (B_ * HW) / threads;          // 8192

    // step 0: carry = frames[:, IL-1, :, :, 0]
    step_kernel<<<blocks, threads, 0, stream>>>(
        frames + (long)(IL_ - 1) * HW, (long)TL_ * HW, 1.0f,
        motion, intensity, evo_result, evo_motion, motion_out, 0);

    // steps 1..P-1: carry = evo_result[:, p-1] * 128 (exact)
    for (int p = 1; p < P_; ++p) {
        step_kernel<<<blocks, threads, 0, stream>>>(
            evo_result + (long)(p - 1) * HW, (long)P_ * HW, 128.0f,
            motion, intensity, evo_result, evo_motion, motion_out, p);
    }
}